// Round 1
// baseline (575.010 us; speedup 1.0000x reference)
//
#include <hip/hip_runtime.h>

// ---------------------------------------------------------------------------
// QuantumNeuralDecoder: B=256 samples, NQ=16 qubits (65536 states), NL=4
// layers, OUT=10.
//
// Circuit:  E(per-sample RY) -> [S_l (16 single-qubit U) -> D_l (diag ZZ)] x4
//           -> <Z_q> -> MLP(16->32->10)
//
// Strategy: merge E into S_1; the state after S_1 is a PRODUCT STATE
// (constructed directly, no read pass). Diagonal D_l is element-wise and can
// be applied in any layout. Two alternating layouts (A: qubits 3..15 local,
// B: qubits 0..2,6..15 local; 8192 amps / 64KB LDS per block) let each pass
// finish the previous layer's 3 leftover gates, apply D, and run 13 gates of
// the next layer => 4 state passes total (~804 MB HBM traffic).
//
// Within a pass: 3 LDS round-trips with 5/4/4-bit gate bundles applied in
// registers (32 amps/thread). LDS XOR swizzle i^((i>>4)&15) gives even bank
// spread for every bundle pattern.
//
// Qubit q <-> global bit (15-q)  (MSB-first, matches the reference reshape).
// ---------------------------------------------------------------------------

struct c32 { float x, y; };

__device__ __forceinline__ c32 cmul(c32 a, c32 b) {
  return { a.x * b.x - a.y * b.y, a.x * b.y + a.y * b.x };
}
__device__ __forceinline__ c32 C32(float2 f) { return { f.x, f.y }; }
__device__ __forceinline__ float2 F2(c32 a) { return make_float2(a.x, a.y); }

__device__ __forceinline__ void gate2(c32 &a0, c32 &a1, const c32 u[4]) {
  c32 b0 = a0, b1 = a1;
  a0.x = u[0].x * b0.x - u[0].y * b0.y + u[1].x * b1.x - u[1].y * b1.y;
  a0.y = u[0].x * b0.y + u[0].y * b0.x + u[1].x * b1.y + u[1].y * b1.x;
  a1.x = u[2].x * b0.x - u[2].y * b0.y + u[3].x * b1.x - u[3].y * b1.y;
  a1.y = u[2].x * b0.y + u[2].y * b0.x + u[3].x * b1.y + u[3].y * b1.x;
}

template <int ST>
__device__ __forceinline__ void apply32(c32 *a, const c32 u[4]) {
#pragma unroll
  for (int p = 0; p < 16; p++) {
    int i0 = ((p & ~(ST - 1)) << 1) | (p & (ST - 1));
    gate2(a[i0], a[i0 + ST], u);
  }
}
template <int ST>
__device__ __forceinline__ void apply16(c32 *a, const c32 u[4]) {
#pragma unroll
  for (int p = 0; p < 8; p++) {
    int i0 = ((p & ~(ST - 1)) << 1) | (p & (ST - 1));
    gate2(a[i0], a[i0 + ST], u);
  }
}

__device__ __forceinline__ void loadU(const float2* __restrict__ Ug, int idx, c32 u[4]) {
#pragma unroll
  for (int k = 0; k < 4; k++) u[k] = C32(Ug[idx * 4 + k]);
}

#define SWZ(i) ((i) ^ (((i) >> 4) & 15))

// U = RX(t0) @ RY(t1) @ RZ(t2)
__device__ __forceinline__ void make_u(float t0, float t1, float t2, c32 u[4]) {
  float cx = cosf(0.5f * t0), sx = sinf(0.5f * t0);
  float cy = cosf(0.5f * t1), sy = sinf(0.5f * t1);
  float cz = cosf(0.5f * t2), sz = sinf(0.5f * t2);
  c32 M00 = {  cx * cy, -sx * sy };
  c32 M01 = { -cx * sy, -sx * cy };
  c32 M10 = {  cx * sy, -sx * cy };
  c32 M11 = {  cx * cy,  sx * sy };
  c32 em = { cz, -sz }, ep = { cz, sz };
  u[0] = cmul(M00, em);
  u[1] = cmul(M01, ep);
  u[2] = cmul(M10, em);
  u[3] = cmul(M11, ep);
}

// Bundle {bits 4..7}: gates q8..q11 of layer lg. In-place LDS RMW.
__device__ __forceinline__ void round2(float2* lds, const float2* __restrict__ Ug,
                                       int lg, int t) {
  c32 u8[4], u9[4], u10[4], u11[4];
  loadU(Ug, lg * 16 + 8,  u8);
  loadU(Ug, lg * 16 + 9,  u9);
  loadU(Ug, lg * 16 + 10, u10);
  loadU(Ug, lg * 16 + 11, u11);
#pragma unroll
  for (int r = 0; r < 2; r++) {
    int G = t + (r << 8);
    int ibase = (G & 15) | ((G >> 4) << 8);
    c32 v[16];
#pragma unroll
    for (int w = 0; w < 16; w++) v[w] = C32(lds[SWZ(ibase | (w << 4))]);
    apply16<8>(v, u8); apply16<4>(v, u9); apply16<2>(v, u10); apply16<1>(v, u11);
#pragma unroll
    for (int w = 0; w < 16; w++) lds[SWZ(ibase | (w << 4))] = F2(v[w]);
  }
}

// Bundle {bits 0..3}: gates q12..q15 of layer lg, then store to global.
// LAYB: layout-B address mapping, else layout-A (contiguous).
template <bool LAYB>
__device__ __forceinline__ void round3(const float2* lds, const float2* __restrict__ Ug,
                                       int lg, int t, float2* __restrict__ gdst, int m) {
  c32 u12[4], u13[4], u14[4], u15[4];
  loadU(Ug, lg * 16 + 12, u12);
  loadU(Ug, lg * 16 + 13, u13);
  loadU(Ug, lg * 16 + 14, u14);
  loadU(Ug, lg * 16 + 15, u15);
#pragma unroll
  for (int r = 0; r < 2; r++) {
    int G = t + (r << 8);
    int ibase = ((G & 15) << 4) | ((G >> 4) << 8);
    c32 v[16];
#pragma unroll
    for (int w = 0; w < 16; w++) v[w] = C32(lds[SWZ(ibase | w)]);
    apply16<8>(v, u12); apply16<4>(v, u13); apply16<2>(v, u14); apply16<1>(v, u15);
    float2* dst;
    if (LAYB) {
      int hi = ibase >> 10, lo = ibase & 1023;
      dst = gdst + (hi << 13) + (m << 10) + lo;
    } else {
      dst = gdst + ibase;
    }
#pragma unroll
    for (int w = 0; w < 16; w += 2) {
      *reinterpret_cast<float4*>(dst + w) = make_float4(v[w].x, v[w].y, v[w + 1].x, v[w + 1].y);
    }
  }
}

// --------------------------- setup kernels ---------------------------------

// angles + per-sample merged gate column v_q = U_{0,q} @ RY(angle)|0>
__global__ __launch_bounds__(256) void k_encode(const float* __restrict__ x,
                                                const float* __restrict__ W,
                                                const float* __restrict__ be,
                                                const float* __restrict__ theta,
                                                float2* __restrict__ vtab) {
  int b = blockIdx.x, t = threadIdx.x;
  int q = t & 15, part = t >> 4;
  const float* xr = x + b * 512;
  float s = 0.f;
#pragma unroll 8
  for (int k = 0; k < 32; k++) {
    int d = part * 32 + k;
    s += xr[d] * W[d * 16 + q];
  }
  __shared__ float red[256];
  red[part * 16 + q] = s;
  __syncthreads();
  for (int st = 8; st > 0; st >>= 1) {
    if (part < st) red[part * 16 + q] += red[(part + st) * 16 + q];
    __syncthreads();
  }
  if (t < 16) {
    float a = tanhf(red[t] + be[t]) * 3.14159265358979323846f;
    float ca = cosf(0.5f * a), sa = sinf(0.5f * a);
    c32 u[4];
    make_u(theta[t * 3 + 0], theta[t * 3 + 1], theta[t * 3 + 2], u);  // layer 0
    float2 v0 = make_float2(u[0].x * ca + u[1].x * sa, u[0].y * ca + u[1].y * sa);
    float2 v1 = make_float2(u[2].x * ca + u[3].x * sa, u[2].y * ca + u[3].y * sa);
    vtab[b * 32 + t * 2]     = v0;
    vtab[b * 32 + t * 2 + 1] = v1;
  }
}

// shared gate matrices for layers 1..3
__global__ void k_gates(const float* __restrict__ theta, float2* __restrict__ Ug) {
  int t = threadIdx.x;
  if (t < 48) {
    int l = t >> 4, q = t & 15;  // layer l+1
    const float* th = theta + ((l + 1) * 16 + q) * 3;
    c32 u[4];
    make_u(th[0], th[1], th[2], u);
#pragma unroll
    for (int k = 0; k < 4; k++) Ug[t * 4 + k] = F2(u[k]);
  }
}

// diagonal ZZ-ring phase tables, 4 layers x 65536
__global__ __launch_bounds__(256) void k_phases(const float* __restrict__ phi,
                                                float2* __restrict__ phtab) {
  int i = blockIdx.x * 256 + threadIdx.x;
#pragma unroll
  for (int l = 0; l < 4; l++) {
    float S = 0.f;
#pragma unroll
    for (int q = 0; q < 16; q++) {
      int sgn = ((i >> (15 - q)) ^ (i >> (15 - ((q + 1) & 15)))) & 1;
      float w = phi[l * 16 + q];
      S += sgn ? -w : w;
    }
    phtab[l * 65536 + i] = make_float2(cosf(0.5f * S), -sinf(0.5f * S));
  }
}

// --------------------------- state passes ----------------------------------

// Pass 1 (layout B: block fixes qubits 3,4,5 = global bits 12..10 = m).
// Construct product state (covers all of S_1), apply D_0, then S_2 on
// {q0,q1,q2,q6,q7} in regs, S_2 {q8..11} (round2), S_2 {q12..15} (round3).
__global__ __launch_bounds__(256) void k_pass1(float2* __restrict__ state,
                                               const float2* __restrict__ vtab,
                                               const float2* __restrict__ Ug,
                                               const float2* __restrict__ phtab) {
  __shared__ float2 lds[8192];
  int b = blockIdx.x >> 3, m = blockIdx.x & 7;
  int t = threadIdx.x;
  const float2* ph0 = phtab;  // layer 0

  // stage v (32 complex) into lds[0..31]
  if (t < 32) lds[t] = vtab[b * 32 + t];
  __syncthreads();
  // T32[j] (qubits 0,1,2,6,7 by j bits 4..0) * cm(q3,q4,q5 by m) -> lds[32..63]
  if (t < 32) {
    int j = t;
    c32 r = C32(lds[0 * 2 + ((j >> 4) & 1)]);
    r = cmul(r, C32(lds[1 * 2 + ((j >> 3) & 1)]));
    r = cmul(r, C32(lds[2 * 2 + ((j >> 2) & 1)]));
    r = cmul(r, C32(lds[6 * 2 + ((j >> 1) & 1)]));
    r = cmul(r, C32(lds[7 * 2 + (j & 1)]));
    r = cmul(r, C32(lds[3 * 2 + ((m >> 2) & 1)]));
    r = cmul(r, C32(lds[4 * 2 + ((m >> 1) & 1)]));
    r = cmul(r, C32(lds[5 * 2 + (m & 1)]));
    lds[32 + j] = F2(r);
  }
  __syncthreads();

  // C(g): qubits 8..15 from g = local bits 7..0 (= global bits 7..0)
  c32 C = { 1.f, 0.f };
#pragma unroll
  for (int q = 8; q < 16; q++) C = cmul(C, C32(lds[q * 2 + ((t >> (15 - q)) & 1)]));

  c32 a[32];
#pragma unroll
  for (int j = 0; j < 32; j++) a[j] = cmul(C, C32(lds[32 + j]));

  // D_0 (element-wise)
#pragma unroll
  for (int j = 0; j < 32; j++) {
    int gidx = ((j >> 2) << 13) | (m << 10) | ((j & 3) << 8) | t;
    a[j] = cmul(a[j], C32(ph0[gidx]));
  }
  // S_2 on bundle-local qubits: q0(b12)=stride16, q1=8, q2=4, q6(b9)=2, q7=1
  c32 u[4];
  loadU(Ug, 0 * 16 + 0, u); apply32<16>(a, u);
  loadU(Ug, 0 * 16 + 1, u); apply32<8>(a, u);
  loadU(Ug, 0 * 16 + 2, u); apply32<4>(a, u);
  loadU(Ug, 0 * 16 + 6, u); apply32<2>(a, u);
  loadU(Ug, 0 * 16 + 7, u); apply32<1>(a, u);
  __syncthreads();  // done reading v/T32 region
#pragma unroll
  for (int j = 0; j < 32; j++) lds[SWZ((j << 8) | t)] = F2(a[j]);
  __syncthreads();
  round2(lds, Ug, 0, t);
  __syncthreads();
  round3<true>(lds, Ug, 0, t, state + ((size_t)b << 16), m);
}

// Pass 2 (layout A: block fixes qubits 0,1,2 = c). S_2{q3,q4,q5}; D_1;
// S_3{q3..q7} in regs; S_3{q8..11}; S_3{q12..15}.
__global__ __launch_bounds__(256) void k_pass2(float2* __restrict__ state,
                                               const float2* __restrict__ Ug,
                                               const float2* __restrict__ phtab) {
  __shared__ float2 lds[8192];
  int b = blockIdx.x >> 3, c = blockIdx.x & 7;
  int t = threadIdx.x;
  const float2* ph1 = phtab + 65536;
  float2* gbase = state + ((size_t)b << 16) + (c << 13);

  c32 a[32];
#pragma unroll
  for (int j = 0; j < 32; j++) a[j] = C32(gbase[(j << 8) | t]);

  c32 u[4];
  loadU(Ug, 0 * 16 + 3, u); apply32<16>(a, u);
  loadU(Ug, 0 * 16 + 4, u); apply32<8>(a, u);
  loadU(Ug, 0 * 16 + 5, u); apply32<4>(a, u);
#pragma unroll
  for (int j = 0; j < 32; j++)
    a[j] = cmul(a[j], C32(ph1[(c << 13) | (j << 8) | t]));
  loadU(Ug, 1 * 16 + 3, u); apply32<16>(a, u);
  loadU(Ug, 1 * 16 + 4, u); apply32<8>(a, u);
  loadU(Ug, 1 * 16 + 5, u); apply32<4>(a, u);
  loadU(Ug, 1 * 16 + 6, u); apply32<2>(a, u);
  loadU(Ug, 1 * 16 + 7, u); apply32<1>(a, u);
#pragma unroll
  for (int j = 0; j < 32; j++) lds[SWZ((j << 8) | t)] = F2(a[j]);
  __syncthreads();
  round2(lds, Ug, 1, t);
  __syncthreads();
  round3<false>(lds, Ug, 1, t, gbase, 0);
}

// Pass 3 (layout B). S_3{q0,q1,q2}; D_2; S_4{q0,q1,q2,q6,q7}; S_4{q8..11};
// S_4{q12..15}.
__global__ __launch_bounds__(256) void k_pass3(float2* __restrict__ state,
                                               const float2* __restrict__ Ug,
                                               const float2* __restrict__ phtab) {
  __shared__ float2 lds[8192];
  int b = blockIdx.x >> 3, m = blockIdx.x & 7;
  int t = threadIdx.x;
  const float2* ph2 = phtab + 2 * 65536;
  float2* sb = state + ((size_t)b << 16);

  c32 a[32];
#pragma unroll
  for (int j = 0; j < 32; j++) {
    int gidx = ((j >> 2) << 13) | (m << 10) | ((j & 3) << 8) | t;
    a[j] = C32(sb[gidx]);
  }
  c32 u[4];
  loadU(Ug, 1 * 16 + 0, u); apply32<16>(a, u);
  loadU(Ug, 1 * 16 + 1, u); apply32<8>(a, u);
  loadU(Ug, 1 * 16 + 2, u); apply32<4>(a, u);
#pragma unroll
  for (int j = 0; j < 32; j++) {
    int gidx = ((j >> 2) << 13) | (m << 10) | ((j & 3) << 8) | t;
    a[j] = cmul(a[j], C32(ph2[gidx]));
  }
  loadU(Ug, 2 * 16 + 0, u); apply32<16>(a, u);
  loadU(Ug, 2 * 16 + 1, u); apply32<8>(a, u);
  loadU(Ug, 2 * 16 + 2, u); apply32<4>(a, u);
  loadU(Ug, 2 * 16 + 6, u); apply32<2>(a, u);
  loadU(Ug, 2 * 16 + 7, u); apply32<1>(a, u);
#pragma unroll
  for (int j = 0; j < 32; j++) lds[SWZ((j << 8) | t)] = F2(a[j]);
  __syncthreads();
  round2(lds, Ug, 2, t);
  __syncthreads();
  round3<true>(lds, Ug, 2, t, sb, m);
}

// Pass 4 (layout A). S_4{q3,q4,q5}; D_3; measure -> per-block z partials.
__global__ __launch_bounds__(256) void k_pass4(const float2* __restrict__ state,
                                               const float2* __restrict__ Ug,
                                               const float2* __restrict__ phtab,
                                               float* __restrict__ zpart) {
  int b = blockIdx.x >> 3, c = blockIdx.x & 7;
  int t = threadIdx.x;
  const float2* ph3 = phtab + 3 * 65536;
  const float2* gbase = state + ((size_t)b << 16) + (c << 13);

  c32 a[32];
#pragma unroll
  for (int j = 0; j < 32; j++) a[j] = C32(gbase[(j << 8) | t]);
  c32 u[4];
  loadU(Ug, 2 * 16 + 3, u); apply32<16>(a, u);
  loadU(Ug, 2 * 16 + 4, u); apply32<8>(a, u);
  loadU(Ug, 2 * 16 + 5, u); apply32<4>(a, u);
#pragma unroll
  for (int j = 0; j < 32; j++)
    a[j] = cmul(a[j], C32(ph3[(c << 13) | (j << 8) | t]));

  float tot = 0.f, acc[5] = { 0.f, 0.f, 0.f, 0.f, 0.f };
#pragma unroll
  for (int j = 0; j < 32; j++) {
    float p = a[j].x * a[j].x + a[j].y * a[j].y;
    tot += p;
#pragma unroll
    for (int k = 0; k < 5; k++) acc[k] += ((j >> (4 - k)) & 1) ? -p : p;
  }
  float vals[14];
  vals[0] = tot;
#pragma unroll
  for (int k = 0; k < 5; k++) vals[1 + k] = acc[k];
#pragma unroll
  for (int q = 8; q < 16; q++) vals[q - 2] = ((t >> (15 - q)) & 1) ? -tot : tot;

#pragma unroll
  for (int off = 32; off > 0; off >>= 1)
#pragma unroll
    for (int k = 0; k < 14; k++) vals[k] += __shfl_down(vals[k], off, 64);

  __shared__ float red[4][14];
  int lane = t & 63, wv = t >> 6;
  if (lane == 0) {
#pragma unroll
    for (int k = 0; k < 14; k++) red[wv][k] = vals[k];
  }
  __syncthreads();
  if (t < 14) {
    float s = red[0][t] + red[1][t] + red[2][t] + red[3][t];
    float* zp = zpart + blockIdx.x * 16;
    if (t == 0) {
      zp[0] = ((c >> 2) & 1) ? -s : s;
      zp[1] = ((c >> 1) & 1) ? -s : s;
      zp[2] = (c & 1) ? -s : s;
    } else {
      zp[t + 2] = s;  // t=1..5 -> q3..7 ; t=6..13 -> q8..15
    }
  }
}

// --------------------------- decoder ---------------------------------------

__global__ __launch_bounds__(256) void k_decode(const float* __restrict__ zpart,
                                                const float* __restrict__ W1,
                                                const float* __restrict__ b1,
                                                const float* __restrict__ W2,
                                                const float* __restrict__ b2,
                                                float* __restrict__ out) {
  int b = threadIdx.x;  // 256 samples
  float z[16];
#pragma unroll
  for (int q = 0; q < 16; q++) {
    float s = 0.f;
#pragma unroll
    for (int cc = 0; cc < 8; cc++) s += zpart[((b << 3) + cc) * 16 + q];
    z[q] = s;
  }
  float o[10];
#pragma unroll
  for (int k = 0; k < 10; k++) o[k] = b2[k];
  for (int j = 0; j < 32; j++) {
    float hj = b1[j];
#pragma unroll
    for (int q = 0; q < 16; q++) hj += z[q] * W1[q * 32 + j];
    hj = fmaxf(hj, 0.f);
#pragma unroll
    for (int k = 0; k < 10; k++) o[k] += hj * W2[j * 10 + k];
  }
#pragma unroll
  for (int k = 0; k < 10; k++) out[b * 10 + k] = o[k];
}

// --------------------------- launcher --------------------------------------

extern "C" void kernel_launch(void* const* d_in, const int* in_sizes, int n_in,
                              void* d_out, int out_size, void* d_ws, size_t ws_size,
                              hipStream_t stream) {
  const float* x     = (const float*)d_in[0];
  const float* Wenc  = (const float*)d_in[1];
  const float* benc  = (const float*)d_in[2];
  const float* theta = (const float*)d_in[3];
  const float* phi   = (const float*)d_in[4];
  const float* W1    = (const float*)d_in[5];
  const float* b1    = (const float*)d_in[6];
  const float* W2    = (const float*)d_in[7];
  const float* b2    = (const float*)d_in[8];
  float* out = (float*)d_out;

  char* w = (char*)d_ws;
  float2* state = (float2*)(w);                    // 256*65536*8 = 134217728 B
  float2* phtab = (float2*)(w + 134217728);        // 4*65536*8   =   2097152 B
  float2* vtab  = (float2*)(w + 136314880);        // 256*32*8    =     65536 B
  float2* Ugtab = (float2*)(w + 136380416);        // 48*4*8      =      1536 B (pad 4096)
  float*  zpart = (float*) (w + 136384512);        // 2048*16*4   =    131072 B

  k_encode<<<256, 256, 0, stream>>>(x, Wenc, benc, theta, vtab);
  k_gates<<<1, 64, 0, stream>>>(theta, Ugtab);
  k_phases<<<256, 256, 0, stream>>>(phi, phtab);
  k_pass1<<<2048, 256, 0, stream>>>(state, vtab, Ugtab, phtab);
  k_pass2<<<2048, 256, 0, stream>>>(state, Ugtab, phtab);
  k_pass3<<<2048, 256, 0, stream>>>(state, Ugtab, phtab);
  k_pass4<<<2048, 256, 0, stream>>>(state, Ugtab, phtab, zpart);
  k_decode<<<1, 256, 0, stream>>>(zpart, W1, b1, W2, b2, out);
}

// Round 2
// 109.704 us; speedup vs baseline: 5.2415x; 5.2415x over previous
//
#include <hip/hip_runtime.h>

// ---------------------------------------------------------------------------
// QuantumNeuralDecoder via EXACT light-cone contraction.
//
// The circuit is: per-sample RY encoding -> 4x [16 single-qubit U; diagonal
// ZZ-ring phase] -> <Z_q> -> MLP. The ZZ entangler is nearest-neighbor on a
// ring with depth 4, so by unitarity <Z_q> depends only on qubits q-4..q+4
// (9 qubits, 512 amplitudes). Per (sample b, qubit q) we simulate the reduced
// circuit with one wave64: 8 amps/lane in registers.
//
// Window bit m (m=0..8) holds qubit j = (q+4-m) mod 16.
//   lane bits 0,1,2  = window bits 0,1,2
//   reg  bits 0,1,2  = window bits 3,4,5   (qubits q+1, q, q-1 -> in-register)
//   lane bits 3,4,5  = window bits 6,7,8
// Cone schedule (forward):
//   init product (encoding+layer0 singles merged into v), D0 (pairs m=1..8),
//   S1 (bits 1..7), D1 (m=2..7), S2 (bits 2..6), D2 (m=3..6),
//   S3 (bits 3..5), D3 (m=4..5), measure window bit 4 (= reg bit 1).
// Diagonal phases come from a precomputed (q,l,i) table (256 KB, L2-hot).
// ---------------------------------------------------------------------------

struct c32 { float x, y; };

__device__ __forceinline__ c32 cmul(c32 a, c32 b) {
  return { a.x * b.x - a.y * b.y, a.x * b.y + a.y * b.x };
}
__device__ __forceinline__ c32 C32(float2 f) { return { f.x, f.y }; }
__device__ __forceinline__ float2 F2(c32 a) { return make_float2(a.x, a.y); }

__device__ __forceinline__ void gate2(c32 &a0, c32 &a1, const c32 u[4]) {
  c32 b0 = a0, b1 = a1;
  a0.x = u[0].x * b0.x - u[0].y * b0.y + u[1].x * b1.x - u[1].y * b1.y;
  a0.y = u[0].x * b0.y + u[0].y * b0.x + u[1].x * b1.y + u[1].y * b1.x;
  a1.x = u[2].x * b0.x - u[2].y * b0.y + u[3].x * b1.x - u[3].y * b1.y;
  a1.y = u[2].x * b0.y + u[2].y * b0.x + u[3].x * b1.y + u[3].y * b1.x;
}

// in-register gate on reg bit (stride ST in the 8-amp array)
template <int ST>
__device__ __forceinline__ void rgate(c32 *a, const c32 u[4]) {
#pragma unroll
  for (int p = 0; p < 4; p++) {
    int i0 = ((p & ~(ST - 1)) << 1) | (p & (ST - 1));
    gate2(a[i0], a[i0 + ST], u);
  }
}

// cross-lane gate on lane bit lb
__device__ __forceinline__ void xgate(c32 *a, const c32 u[4], int lb, int lane) {
  bool hi = (lane >> lb) & 1;
  c32 ua = hi ? u[3] : u[0];  // coeff of own amp
  c32 ub = hi ? u[2] : u[1];  // coeff of partner amp
  int mask = 1 << lb;
#pragma unroll
  for (int r = 0; r < 8; r++) {
    float px = __shfl_xor(a[r].x, mask, 64);
    float py = __shfl_xor(a[r].y, mask, 64);
    c32 o = a[r];
    a[r].x = ua.x * o.x - ua.y * o.y + ub.x * px - ub.y * py;
    a[r].y = ua.x * o.y + ua.y * o.x + ub.x * py + ub.y * px;
  }
}

__device__ __forceinline__ void loadU(const float2* __restrict__ Ug, int idx, c32 u[4]) {
#pragma unroll
  for (int k = 0; k < 4; k++) u[k] = C32(Ug[idx * 4 + k]);
}

// U = RX(t0) @ RY(t1) @ RZ(t2)
__device__ __forceinline__ void make_u(float t0, float t1, float t2, c32 u[4]) {
  float cx = cosf(0.5f * t0), sx = sinf(0.5f * t0);
  float cy = cosf(0.5f * t1), sy = sinf(0.5f * t1);
  float cz = cosf(0.5f * t2), sz = sinf(0.5f * t2);
  c32 M00 = {  cx * cy, -sx * sy };
  c32 M01 = { -cx * sy, -sx * cy };
  c32 M10 = {  cx * sy, -sx * cy };
  c32 M11 = {  cx * cy,  sx * sy };
  c32 em = { cz, -sz }, ep = { cz, sz };
  u[0] = cmul(M00, em);
  u[1] = cmul(M01, ep);
  u[2] = cmul(M10, em);
  u[3] = cmul(M11, ep);
}

// --------------------------- setup kernels ---------------------------------

// per-sample merged column v_q = U_{layer0,q} @ RY(angle_q)|0>  (2 c32 per q)
__global__ __launch_bounds__(256) void k_encode(const float* __restrict__ x,
                                                const float* __restrict__ W,
                                                const float* __restrict__ be,
                                                const float* __restrict__ theta,
                                                float2* __restrict__ vtab) {
  int b = blockIdx.x, t = threadIdx.x;
  int q = t & 15, part = t >> 4;
  const float* xr = x + b * 512;
  float s = 0.f;
#pragma unroll 8
  for (int k = 0; k < 32; k++) {
    int d = part * 32 + k;
    s += xr[d] * W[d * 16 + q];
  }
  __shared__ float red[256];
  red[part * 16 + q] = s;
  __syncthreads();
  for (int st = 8; st > 0; st >>= 1) {
    if (part < st) red[part * 16 + q] += red[(part + st) * 16 + q];
    __syncthreads();
  }
  if (t < 16) {
    float a = tanhf(red[t] + be[t]) * 3.14159265358979323846f;
    float ca = cosf(0.5f * a), sa = sinf(0.5f * a);
    c32 u[4];
    make_u(theta[t * 3 + 0], theta[t * 3 + 1], theta[t * 3 + 2], u);  // layer 0
    vtab[b * 32 + t * 2]     = make_float2(u[0].x * ca + u[1].x * sa,
                                           u[0].y * ca + u[1].y * sa);
    vtab[b * 32 + t * 2 + 1] = make_float2(u[2].x * ca + u[3].x * sa,
                                           u[2].y * ca + u[3].y * sa);
  }
}

// gate table (layers 1..3, 48 gates) + cone phase table qph[q][l][i] (16*4*512)
__global__ __launch_bounds__(256) void k_tables(const float* __restrict__ theta,
                                                const float* __restrict__ phi,
                                                float2* __restrict__ Ug,
                                                float2* __restrict__ qph) {
  int idx = blockIdx.x * 256 + threadIdx.x;   // 0..32767
  if (idx < 48) {
    int l = idx >> 4, qq = idx & 15;          // layer l+1
    const float* th = theta + ((l + 1) * 16 + qq) * 3;
    c32 u[4];
    make_u(th[0], th[1], th[2], u);
#pragma unroll
    for (int k = 0; k < 4; k++) Ug[idx * 4 + k] = F2(u[k]);
  }
  int q = idx >> 11, l = (idx >> 9) & 3, i = idx & 511;
  float A = 0.f;
  for (int m = l + 1; m <= 8 - l; m++) {
    int j = (q + 4 - m) & 15;                 // ring pair (j, j+1) = bits (m, m-1)
    float wv = phi[l * 16 + j];
    int sg = ((i >> m) ^ (i >> (m - 1))) & 1;
    A += sg ? -wv : wv;
  }
  qph[idx] = make_float2(cosf(0.5f * A), -sinf(0.5f * A));
}

// --------------------------- cone simulation -------------------------------

__global__ __launch_bounds__(256) void k_cone(const float2* __restrict__ vtab,
                                              const float2* __restrict__ Ug,
                                              const float2* __restrict__ qph,
                                              float* __restrict__ zbuf) {
  int w = blockIdx.x * 4 + (threadIdx.x >> 6);
  int lane = threadIdx.x & 63;
  int b = w >> 4, q = w & 15;

  // v per window bit m: qubit j = (q+4-m) & 15
  c32 vv[9][2];
#pragma unroll
  for (int m = 0; m < 9; m++) {
    int jj = (q + 4 - m) & 15;
    vv[m][0] = C32(vtab[b * 32 + jj * 2]);
    vv[m][1] = C32(vtab[b * 32 + jj * 2 + 1]);
  }

  // product init: lane bits 0,1,2 -> window bits 0,1,2; lane bits 3,4,5 -> 6,7,8
  c32 lp = vv[0][lane & 1];
  lp = cmul(lp, vv[1][(lane >> 1) & 1]);
  lp = cmul(lp, vv[2][(lane >> 2) & 1]);
  lp = cmul(lp, vv[6][(lane >> 3) & 1]);
  lp = cmul(lp, vv[7][(lane >> 4) & 1]);
  lp = cmul(lp, vv[8][(lane >> 5) & 1]);

  c32 a[8];
#pragma unroll
  for (int r = 0; r < 8; r++) {
    c32 t = cmul(vv[3][r & 1], vv[4][(r >> 1) & 1]);
    t = cmul(t, vv[5][(r >> 2) & 1]);
    a[r] = cmul(lp, t);
  }

  const float2* ph = qph + q * 2048;
  int ibase = (lane & 7) | (((lane >> 3) & 7) << 6);

  c32 u[4];
  // ---- D0 ----
#pragma unroll
  for (int r = 0; r < 8; r++) a[r] = cmul(a[r], C32(ph[ibase | (r << 3)]));
  // ---- S1 on window bits 1..7 (layer slot 0) ----
  loadU(Ug, 0 * 16 + ((q + 3) & 15), u); xgate(a, u, 1, lane);   // m=1
  loadU(Ug, 0 * 16 + ((q + 2) & 15), u); xgate(a, u, 2, lane);   // m=2
  loadU(Ug, 0 * 16 + ((q + 1) & 15), u); rgate<1>(a, u);         // m=3
  loadU(Ug, 0 * 16 + ( q          ), u); rgate<2>(a, u);         // m=4
  loadU(Ug, 0 * 16 + ((q - 1) & 15), u); rgate<4>(a, u);         // m=5
  loadU(Ug, 0 * 16 + ((q - 2) & 15), u); xgate(a, u, 3, lane);   // m=6
  loadU(Ug, 0 * 16 + ((q - 3) & 15), u); xgate(a, u, 4, lane);   // m=7
  // ---- D1 ----
#pragma unroll
  for (int r = 0; r < 8; r++) a[r] = cmul(a[r], C32(ph[512 | ibase | (r << 3)]));
  // ---- S2 on window bits 2..6 (layer slot 1) ----
  loadU(Ug, 1 * 16 + ((q + 2) & 15), u); xgate(a, u, 2, lane);   // m=2
  loadU(Ug, 1 * 16 + ((q + 1) & 15), u); rgate<1>(a, u);         // m=3
  loadU(Ug, 1 * 16 + ( q          ), u); rgate<2>(a, u);         // m=4
  loadU(Ug, 1 * 16 + ((q - 1) & 15), u); rgate<4>(a, u);         // m=5
  loadU(Ug, 1 * 16 + ((q - 2) & 15), u); xgate(a, u, 3, lane);   // m=6
  // ---- D2 ----
#pragma unroll
  for (int r = 0; r < 8; r++) a[r] = cmul(a[r], C32(ph[1024 | ibase | (r << 3)]));
  // ---- S3 on window bits 3..5 (layer slot 2) ----
  loadU(Ug, 2 * 16 + ((q + 1) & 15), u); rgate<1>(a, u);         // m=3
  loadU(Ug, 2 * 16 + ( q          ), u); rgate<2>(a, u);         // m=4
  loadU(Ug, 2 * 16 + ((q - 1) & 15), u); rgate<4>(a, u);         // m=5
  // ---- D3 ----
#pragma unroll
  for (int r = 0; r < 8; r++) a[r] = cmul(a[r], C32(ph[1536 | ibase | (r << 3)]));

  // ---- measure Z_q: window bit 4 = reg bit 1 ----
  float z = 0.f;
#pragma unroll
  for (int r = 0; r < 8; r++) {
    float p = a[r].x * a[r].x + a[r].y * a[r].y;
    z += ((r >> 1) & 1) ? -p : p;
  }
#pragma unroll
  for (int off = 32; off > 0; off >>= 1) z += __shfl_xor(z, off, 64);
  if (lane == 0) zbuf[b * 16 + q] = z;
}

// --------------------------- decoder ---------------------------------------

__global__ __launch_bounds__(256) void k_decode(const float* __restrict__ zbuf,
                                                const float* __restrict__ W1,
                                                const float* __restrict__ b1,
                                                const float* __restrict__ W2,
                                                const float* __restrict__ b2,
                                                float* __restrict__ out) {
  int b = threadIdx.x;  // 256 samples
  float z[16];
#pragma unroll
  for (int q = 0; q < 16; q++) z[q] = zbuf[b * 16 + q];
  float o[10];
#pragma unroll
  for (int k = 0; k < 10; k++) o[k] = b2[k];
  for (int j = 0; j < 32; j++) {
    float hj = b1[j];
#pragma unroll
    for (int q = 0; q < 16; q++) hj += z[q] * W1[q * 32 + j];
    hj = fmaxf(hj, 0.f);
#pragma unroll
    for (int k = 0; k < 10; k++) o[k] += hj * W2[j * 10 + k];
  }
#pragma unroll
  for (int k = 0; k < 10; k++) out[b * 10 + k] = o[k];
}

// --------------------------- launcher --------------------------------------

extern "C" void kernel_launch(void* const* d_in, const int* in_sizes, int n_in,
                              void* d_out, int out_size, void* d_ws, size_t ws_size,
                              hipStream_t stream) {
  const float* x     = (const float*)d_in[0];
  const float* Wenc  = (const float*)d_in[1];
  const float* benc  = (const float*)d_in[2];
  const float* theta = (const float*)d_in[3];
  const float* phi   = (const float*)d_in[4];
  const float* W1    = (const float*)d_in[5];
  const float* b1    = (const float*)d_in[6];
  const float* W2    = (const float*)d_in[7];
  const float* b2    = (const float*)d_in[8];
  float* out = (float*)d_out;

  char* w = (char*)d_ws;
  float2* vtab = (float2*)(w);              // 256*32*8   = 65536 B
  float2* Ugtab = (float2*)(w + 65536);     // 48*4*8     =  1536 B (pad to 4096)
  float2* qph  = (float2*)(w + 69632);      // 16*4*512*8 = 262144 B
  float*  zbuf = (float*) (w + 331776);     // 256*16*4   =  16384 B

  k_encode<<<256, 256, 0, stream>>>(x, Wenc, benc, theta, vtab);
  k_tables<<<128, 256, 0, stream>>>(theta, phi, Ugtab, qph);
  k_cone<<<1024, 256, 0, stream>>>(vtab, Ugtab, qph, zbuf);
  k_decode<<<1, 256, 0, stream>>>(zbuf, W1, b1, W2, b2, out);
}

// Round 3
// 83.306 us; speedup vs baseline: 6.9024x; 1.3169x over previous
//
#include <hip/hip_runtime.h>

// ---------------------------------------------------------------------------
// QuantumNeuralDecoder via EXACT light-cone contraction (R3).
//
// <Z_q> depends only on the 9-qubit causal cone q-4..q+4 (ZZ ring, depth 4).
// Per (sample b, qubit q): one wave64 simulates the 512-amp reduced circuit,
// 8 amps/lane in REGISTERS (R2's scratch-spill from dynamic indexing fixed:
// vv split into vv0/vv1 with static indices + cndmask selects).
//
// Window bit m (m=0..8) holds qubit j = (q+4-m) mod 16.
//   lane bits 0,1,2 = window bits 0,1,2
//   reg  bits 0,1,2 = window bits 3,4,5
//   lane bits 3,4,5 = window bits 6,7,8
// Schedule: product init (encoding+layer0 merged) -> D0 -> S1(bits1..7) ->
//           D1 -> S2(bits2..6) -> D2 -> S3(bits3..5) -> D3 -> measure bit4.
//
// Two launches total: k_prep (encode vtab + gate/phase tables) and
// k_cone_decode (cone sim + in-block MLP decode; block = sample, wave = q).
// ---------------------------------------------------------------------------

struct c32 { float x, y; };

__device__ __forceinline__ c32 cmul(c32 a, c32 b) {
  return { a.x * b.x - a.y * b.y, a.x * b.y + a.y * b.x };
}
__device__ __forceinline__ c32 C32(float2 f) { return { f.x, f.y }; }
__device__ __forceinline__ float2 F2(c32 a) { return make_float2(a.x, a.y); }
__device__ __forceinline__ c32 csel(c32 a, c32 b, int s) {
  return { s ? b.x : a.x, s ? b.y : a.y };
}

__device__ __forceinline__ void gate2(c32 &a0, c32 &a1, const c32 u[4]) {
  c32 b0 = a0, b1 = a1;
  a0.x = u[0].x * b0.x - u[0].y * b0.y + u[1].x * b1.x - u[1].y * b1.y;
  a0.y = u[0].x * b0.y + u[0].y * b0.x + u[1].x * b1.y + u[1].y * b1.x;
  a1.x = u[2].x * b0.x - u[2].y * b0.y + u[3].x * b1.x - u[3].y * b1.y;
  a1.y = u[2].x * b0.y + u[2].y * b0.x + u[3].x * b1.y + u[3].y * b1.x;
}

template <int ST>
__device__ __forceinline__ void rgate(c32 *a, const c32 u[4]) {
#pragma unroll
  for (int p = 0; p < 4; p++) {
    int i0 = ((p & ~(ST - 1)) << 1) | (p & (ST - 1));
    gate2(a[i0], a[i0 + ST], u);
  }
}

__device__ __forceinline__ void xgate(c32 *a, const c32 u[4], int lb, int lane) {
  int hi = (lane >> lb) & 1;
  c32 ua = csel(u[0], u[3], hi);  // coeff of own amp
  c32 ub = csel(u[1], u[2], hi);  // coeff of partner amp
  int mask = 1 << lb;
#pragma unroll
  for (int r = 0; r < 8; r++) {
    float px = __shfl_xor(a[r].x, mask, 64);
    float py = __shfl_xor(a[r].y, mask, 64);
    c32 o = a[r];
    a[r].x = ua.x * o.x - ua.y * o.y + ub.x * px - ub.y * py;
    a[r].y = ua.x * o.y + ua.y * o.x + ub.x * py + ub.y * px;
  }
}

__device__ __forceinline__ void loadU(const float2* __restrict__ Ug, int idx, c32 u[4]) {
#pragma unroll
  for (int k = 0; k < 4; k++) u[k] = C32(Ug[idx * 4 + k]);
}

// U = RX(t0) @ RY(t1) @ RZ(t2)
__device__ __forceinline__ void make_u(float t0, float t1, float t2, c32 u[4]) {
  float cx = cosf(0.5f * t0), sx = sinf(0.5f * t0);
  float cy = cosf(0.5f * t1), sy = sinf(0.5f * t1);
  float cz = cosf(0.5f * t2), sz = sinf(0.5f * t2);
  c32 M00 = {  cx * cy, -sx * sy };
  c32 M01 = { -cx * sy, -sx * cy };
  c32 M10 = {  cx * sy, -sx * cy };
  c32 M11 = {  cx * cy,  sx * sy };
  c32 em = { cz, -sz }, ep = { cz, sz };
  u[0] = cmul(M00, em);
  u[1] = cmul(M01, ep);
  u[2] = cmul(M10, em);
  u[3] = cmul(M11, ep);
}

// --------------------------- prep kernel -----------------------------------
// blocks 0..255: per-sample encoding -> vtab (merged RY(angle) @ layer0 U col)
// blocks 256..383: gate table Ug (layers 1..3) + phase table qph[q][l][i]

__global__ __launch_bounds__(256) void k_prep(const float* __restrict__ x,
                                              const float* __restrict__ W,
                                              const float* __restrict__ be,
                                              const float* __restrict__ theta,
                                              const float* __restrict__ phi,
                                              float2* __restrict__ vtab,
                                              float2* __restrict__ Ug,
                                              float2* __restrict__ qph) {
  int t = threadIdx.x;
  if (blockIdx.x < 256) {
    int b = blockIdx.x;
    int q = t & 15, part = t >> 4;
    const float* xr = x + b * 512;
    float s = 0.f;
#pragma unroll 8
    for (int k = 0; k < 32; k++) {
      int d = part * 32 + k;
      s += xr[d] * W[d * 16 + q];
    }
    __shared__ float red[256];
    red[part * 16 + q] = s;
    __syncthreads();
    for (int st = 8; st > 0; st >>= 1) {
      if (part < st) red[part * 16 + q] += red[(part + st) * 16 + q];
      __syncthreads();
    }
    if (t < 16) {
      float a = tanhf(red[t] + be[t]) * 3.14159265358979323846f;
      float ca = cosf(0.5f * a), sa = sinf(0.5f * a);
      c32 u[4];
      make_u(theta[t * 3 + 0], theta[t * 3 + 1], theta[t * 3 + 2], u);  // layer 0
      vtab[b * 32 + t * 2]     = make_float2(u[0].x * ca + u[1].x * sa,
                                             u[0].y * ca + u[1].y * sa);
      vtab[b * 32 + t * 2 + 1] = make_float2(u[2].x * ca + u[3].x * sa,
                                             u[2].y * ca + u[3].y * sa);
    }
  } else {
    int idx = (blockIdx.x - 256) * 256 + t;   // 0..32767
    if (idx < 48) {
      int l = idx >> 4, qq = idx & 15;        // layer l+1
      const float* th = theta + ((l + 1) * 16 + qq) * 3;
      c32 u[4];
      make_u(th[0], th[1], th[2], u);
#pragma unroll
      for (int k = 0; k < 4; k++) Ug[idx * 4 + k] = F2(u[k]);
    }
    int q = idx >> 11, l = (idx >> 9) & 3, i = idx & 511;
    float A = 0.f;
    for (int m = l + 1; m <= 8 - l; m++) {
      int j = (q + 4 - m) & 15;               // ring pair (j, j+1) = bits (m, m-1)
      float wv = phi[l * 16 + j];
      int sg = ((i >> m) ^ (i >> (m - 1))) & 1;
      A += sg ? -wv : wv;
    }
    qph[idx] = make_float2(cosf(0.5f * A), -sinf(0.5f * A));
  }
}

// --------------------------- cone + decode ---------------------------------

__global__ __launch_bounds__(1024) void k_cone_decode(const float2* __restrict__ vtab,
                                                      const float2* __restrict__ Ug,
                                                      const float2* __restrict__ qph,
                                                      const float* __restrict__ W1,
                                                      const float* __restrict__ b1,
                                                      const float* __restrict__ W2,
                                                      const float* __restrict__ b2,
                                                      float* __restrict__ out) {
  int b = blockIdx.x;
  int tid = threadIdx.x;
  int q = tid >> 6, lane = tid & 63;

  // v per window bit m: qubit j = (q+4-m) & 15 ; STATIC indices only.
  c32 vv0[9], vv1[9];
  const float2* vt = vtab + b * 32;
#pragma unroll
  for (int m = 0; m < 9; m++) {
    int jj = (q + 4 - m) & 15;
    vv0[m] = C32(vt[jj * 2]);
    vv1[m] = C32(vt[jj * 2 + 1]);
  }

  // product init: lane bits 0,1,2 -> window 0,1,2 ; lane bits 3,4,5 -> 6,7,8
  c32 lp = csel(vv0[0], vv1[0], lane & 1);
  lp = cmul(lp, csel(vv0[1], vv1[1], (lane >> 1) & 1));
  lp = cmul(lp, csel(vv0[2], vv1[2], (lane >> 2) & 1));
  lp = cmul(lp, csel(vv0[6], vv1[6], (lane >> 3) & 1));
  lp = cmul(lp, csel(vv0[7], vv1[7], (lane >> 4) & 1));
  lp = cmul(lp, csel(vv0[8], vv1[8], (lane >> 5) & 1));

  c32 a[8];
#pragma unroll
  for (int r = 0; r < 8; r++) {   // r compile-time after unroll -> static picks
    c32 tt = cmul(((r & 1) ? vv1[3] : vv0[3]), (((r >> 1) & 1) ? vv1[4] : vv0[4]));
    tt = cmul(tt, (((r >> 2) & 1) ? vv1[5] : vv0[5]));
    a[r] = cmul(lp, tt);
  }

  const float2* ph = qph + q * 2048;
  int ibase = (lane & 7) | (((lane >> 3) & 7) << 6);

  c32 u[4];
  // ---- D0 ----
#pragma unroll
  for (int r = 0; r < 8; r++) a[r] = cmul(a[r], C32(ph[ibase | (r << 3)]));
  // ---- S1 on window bits 1..7 (layer slot 0) ----
  loadU(Ug, 0 * 16 + ((q + 3) & 15), u); xgate(a, u, 1, lane);   // m=1
  loadU(Ug, 0 * 16 + ((q + 2) & 15), u); xgate(a, u, 2, lane);   // m=2
  loadU(Ug, 0 * 16 + ((q + 1) & 15), u); rgate<1>(a, u);         // m=3
  loadU(Ug, 0 * 16 + ( q          ), u); rgate<2>(a, u);         // m=4
  loadU(Ug, 0 * 16 + ((q - 1) & 15), u); rgate<4>(a, u);         // m=5
  loadU(Ug, 0 * 16 + ((q - 2) & 15), u); xgate(a, u, 3, lane);   // m=6
  loadU(Ug, 0 * 16 + ((q - 3) & 15), u); xgate(a, u, 4, lane);   // m=7
  // ---- D1 ----
#pragma unroll
  for (int r = 0; r < 8; r++) a[r] = cmul(a[r], C32(ph[512 | ibase | (r << 3)]));
  // ---- S2 on window bits 2..6 (layer slot 1) ----
  loadU(Ug, 1 * 16 + ((q + 2) & 15), u); xgate(a, u, 2, lane);   // m=2
  loadU(Ug, 1 * 16 + ((q + 1) & 15), u); rgate<1>(a, u);         // m=3
  loadU(Ug, 1 * 16 + ( q          ), u); rgate<2>(a, u);         // m=4
  loadU(Ug, 1 * 16 + ((q - 1) & 15), u); rgate<4>(a, u);         // m=5
  loadU(Ug, 1 * 16 + ((q - 2) & 15), u); xgate(a, u, 3, lane);   // m=6
  // ---- D2 ----
#pragma unroll
  for (int r = 0; r < 8; r++) a[r] = cmul(a[r], C32(ph[1024 | ibase | (r << 3)]));
  // ---- S3 on window bits 3..5 (layer slot 2) ----
  loadU(Ug, 2 * 16 + ((q + 1) & 15), u); rgate<1>(a, u);         // m=3
  loadU(Ug, 2 * 16 + ( q          ), u); rgate<2>(a, u);         // m=4
  loadU(Ug, 2 * 16 + ((q - 1) & 15), u); rgate<4>(a, u);         // m=5
  // ---- D3 ----
#pragma unroll
  for (int r = 0; r < 8; r++) a[r] = cmul(a[r], C32(ph[1536 | ibase | (r << 3)]));

  // ---- measure Z_q: window bit 4 = reg bit 1 ----
  float z = 0.f;
#pragma unroll
  for (int r = 0; r < 8; r++) {
    float p = a[r].x * a[r].x + a[r].y * a[r].y;
    z += ((r >> 1) & 1) ? -p : p;
  }
#pragma unroll
  for (int off = 32; off > 0; off >>= 1) z += __shfl_xor(z, off, 64);

  // ---- in-block MLP decode ----
  __shared__ float zsh[16];
  __shared__ float hsh[32];
  if (lane == 0) zsh[q] = z;
  __syncthreads();
  if (tid < 32) {
    float hj = b1[tid];
#pragma unroll
    for (int qq = 0; qq < 16; qq++) hj += zsh[qq] * W1[qq * 32 + tid];
    hsh[tid] = fmaxf(hj, 0.f);
  }
  __syncthreads();
  if (tid < 10) {
    float o = b2[tid];
#pragma unroll
    for (int j = 0; j < 32; j++) o += hsh[j] * W2[j * 10 + tid];
    out[b * 10 + tid] = o;
  }
}

// --------------------------- launcher --------------------------------------

extern "C" void kernel_launch(void* const* d_in, const int* in_sizes, int n_in,
                              void* d_out, int out_size, void* d_ws, size_t ws_size,
                              hipStream_t stream) {
  const float* x     = (const float*)d_in[0];
  const float* Wenc  = (const float*)d_in[1];
  const float* benc  = (const float*)d_in[2];
  const float* theta = (const float*)d_in[3];
  const float* phi   = (const float*)d_in[4];
  const float* W1    = (const float*)d_in[5];
  const float* b1    = (const float*)d_in[6];
  const float* W2    = (const float*)d_in[7];
  const float* b2    = (const float*)d_in[8];
  float* out = (float*)d_out;

  char* w = (char*)d_ws;
  float2* vtab  = (float2*)(w);             // 256*32*8   = 65536 B
  float2* Ugtab = (float2*)(w + 65536);     // 48*4*8     =  1536 B (pad to 4096)
  float2* qph   = (float2*)(w + 69632);     // 16*4*512*8 = 262144 B

  k_prep<<<384, 256, 0, stream>>>(x, Wenc, benc, theta, phi, vtab, Ugtab, qph);
  k_cone_decode<<<256, 1024, 0, stream>>>(vtab, Ugtab, qph, W1, b1, W2, b2, out);
}

// Round 4
// 80.955 us; speedup vs baseline: 7.1028x; 1.0290x over previous
//
#include <hip/hip_runtime.h>

// ---------------------------------------------------------------------------
// QuantumNeuralDecoder via EXACT light-cone contraction — single fused kernel.
//
// <Z_q> depends only on the 9-qubit causal cone q-4..q+4 (ZZ ring, depth 4).
// Block = sample b (256 blocks x 1024 threads); wave w = qubit q; 512-amp
// reduced state as 8 amps/lane in registers.
//
// Window bit m (m=0..8) holds qubit j = (q+4-m) mod 16.
//   lane bits 0,1,2 = window bits 0,1,2
//   reg  bits 0,1,2 = window bits 3,4,5
//   lane bits 3,4,5 = window bits 6,7,8
//
// R4 changes vs R3:
//  - ONE kernel: per-block encode (x@W_enc -> angles -> merged layer-0 col),
//    per-block gate table (48 gates, redundant but ~free), in-block MLP.
//  - Diagonal ZZ phases computed ANALYTICALLY per lane (no qph table):
//    per layer, lane-only terms fold into scalar L; cross terms (window bits
//    3/2 and 6/5) pre-signed by lane bit -> per-r signs are compile-time.
//  - D3 dropped: a pure phase right before Z-measurement is unobservable.
// ---------------------------------------------------------------------------

struct c32 { float x, y; };

__device__ __forceinline__ c32 cmul(c32 a, c32 b) {
  return { a.x * b.x - a.y * b.y, a.x * b.y + a.y * b.x };
}
__device__ __forceinline__ c32 C32(float2 f) { return { f.x, f.y }; }
__device__ __forceinline__ float2 F2(c32 a) { return make_float2(a.x, a.y); }
__device__ __forceinline__ c32 csel(c32 a, c32 b, int s) {
  return { s ? b.x : a.x, s ? b.y : a.y };
}
__device__ __forceinline__ float fsgn(int s, float w) { return s ? -w : w; }

__device__ __forceinline__ void gate2(c32 &a0, c32 &a1, const c32 u[4]) {
  c32 b0 = a0, b1 = a1;
  a0.x = u[0].x * b0.x - u[0].y * b0.y + u[1].x * b1.x - u[1].y * b1.y;
  a0.y = u[0].x * b0.y + u[0].y * b0.x + u[1].x * b1.y + u[1].y * b1.x;
  a1.x = u[2].x * b0.x - u[2].y * b0.y + u[3].x * b1.x - u[3].y * b1.y;
  a1.y = u[2].x * b0.y + u[2].y * b0.x + u[3].x * b1.y + u[3].y * b1.x;
}

template <int ST>
__device__ __forceinline__ void rgate(c32 *a, const c32 u[4]) {
#pragma unroll
  for (int p = 0; p < 4; p++) {
    int i0 = ((p & ~(ST - 1)) << 1) | (p & (ST - 1));
    gate2(a[i0], a[i0 + ST], u);
  }
}

__device__ __forceinline__ void xgate(c32 *a, const c32 u[4], int lb, int lane) {
  int hi = (lane >> lb) & 1;
  c32 ua = csel(u[0], u[3], hi);  // coeff of own amp
  c32 ub = csel(u[1], u[2], hi);  // coeff of partner amp
  int mask = 1 << lb;
#pragma unroll
  for (int r = 0; r < 8; r++) {
    float px = __shfl_xor(a[r].x, mask, 64);
    float py = __shfl_xor(a[r].y, mask, 64);
    c32 o = a[r];
    a[r].x = ua.x * o.x - ua.y * o.y + ub.x * px - ub.y * py;
    a[r].y = ua.x * o.y + ua.y * o.x + ub.x * py + ub.y * px;
  }
}

__device__ __forceinline__ void loadU(const float2* Ug, int idx, c32 u[4]) {
#pragma unroll
  for (int k = 0; k < 4; k++) u[k] = C32(Ug[idx * 4 + k]);
}

// U = RX(t0) @ RY(t1) @ RZ(t2)
__device__ __forceinline__ void make_u(float t0, float t1, float t2, c32 u[4]) {
  float cx = cosf(0.5f * t0), sx = sinf(0.5f * t0);
  float cy = cosf(0.5f * t1), sy = sinf(0.5f * t1);
  float cz = cosf(0.5f * t2), sz = sinf(0.5f * t2);
  c32 M00 = {  cx * cy, -sx * sy };
  c32 M01 = { -cx * sy, -sx * cy };
  c32 M10 = {  cx * sy, -sx * cy };
  c32 M11 = {  cx * cy,  sx * sy };
  c32 em = { cz, -sz }, ep = { cz, sz };
  u[0] = cmul(M00, em);
  u[1] = cmul(M01, ep);
  u[2] = cmul(M10, em);
  u[3] = cmul(M11, ep);
}

// diagonal layer applied to 8 regs: A(r) = L +-w3p +-w4 +-w5 +-w6p, signs
// compile-time per r after unroll; weights are pre-halved (phase = e^{-iA}).
__device__ __forceinline__ void diag8(c32 *a, float L, float w3p, float w4,
                                      float w5, float w6p) {
#pragma unroll
  for (int r = 0; r < 8; r++) {
    int r0 = r & 1, r1 = (r >> 1) & 1, r2 = (r >> 2) & 1;
    float A = L + (r0 ? -w3p : w3p) + ((r1 ^ r0) ? -w4 : w4)
                + ((r2 ^ r1) ? -w5 : w5) + (r2 ? -w6p : w6p);
    c32 p = { __cosf(A), -__sinf(A) };
    a[r] = cmul(a[r], p);
  }
}

// --------------------------- fused kernel ----------------------------------

__global__ __launch_bounds__(1024) void k_all(const float* __restrict__ x,
                                              const float* __restrict__ W,
                                              const float* __restrict__ be,
                                              const float* __restrict__ theta,
                                              const float* __restrict__ phi,
                                              const float* __restrict__ W1,
                                              const float* __restrict__ b1,
                                              const float* __restrict__ W2,
                                              const float* __restrict__ b2,
                                              float* __restrict__ out) {
  __shared__ float  red[256];     // per-wave encode partials [wave][q]
  __shared__ float2 vsh[32];      // merged encoding columns (16 qubits x 2)
  __shared__ float2 ugsh[192];    // 48 gates x 4 (layers 1..3)
  __shared__ float  phish[64];    // 0.5 * phi
  __shared__ float  zsh[16];
  __shared__ float  hsh[32];

  int tid = threadIdx.x, b = blockIdx.x;
  int lane = tid & 63, wv = tid >> 6;

  // ---- encode: angles = tanh(x@W + be) * pi ; 64 parts x 16 q ----
  {
    int q16 = tid & 15, part = tid >> 4;
    const float* xr = x + (b << 9);
    float s = 0.f;
#pragma unroll
    for (int k = 0; k < 8; k++) {
      int d = (part << 3) + k;
      s += xr[d] * W[(d << 4) + q16];
    }
    s += __shfl_xor(s, 16, 64);
    s += __shfl_xor(s, 32, 64);   // sum over this wave's 4 parts
    if (lane < 16) red[wv * 16 + lane] = s;
  }
  // gate table + phi staging on high waves (independent of red)
  if (tid >= 960 && tid < 1008) {
    int gl = tid - 960, l = gl >> 4, qq = gl & 15;
    const float* th = theta + (((l + 1) << 4) + qq) * 3;
    c32 u[4];
    make_u(th[0], th[1], th[2], u);
#pragma unroll
    for (int k = 0; k < 4; k++) ugsh[gl * 4 + k] = F2(u[k]);
  } else if (tid >= 896 && tid < 960) {
    phish[tid - 896] = 0.5f * phi[tid - 896];
  }
  __syncthreads();
  if (tid < 16) {
    float acc = 0.f;
#pragma unroll
    for (int w = 0; w < 16; w++) acc += red[w * 16 + tid];
    float a = tanhf(acc + be[tid]) * 3.14159265358979323846f;
    float ca = __cosf(0.5f * a), sa = __sinf(0.5f * a);
    c32 u[4];
    make_u(theta[tid * 3 + 0], theta[tid * 3 + 1], theta[tid * 3 + 2], u);  // layer 0
    vsh[tid * 2]     = make_float2(u[0].x * ca + u[1].x * sa,
                                   u[0].y * ca + u[1].y * sa);
    vsh[tid * 2 + 1] = make_float2(u[2].x * ca + u[3].x * sa,
                                   u[2].y * ca + u[3].y * sa);
  }
  __syncthreads();

  // ---- cone simulation: wave wv handles qubit q = wv ----
  int q = wv;
  int lb0 = lane & 1, lb1 = (lane >> 1) & 1, lb2 = (lane >> 2) & 1;
  int lb3 = (lane >> 3) & 1, lb4 = (lane >> 4) & 1, lb5 = (lane >> 5) & 1;

  c32 vv0[9], vv1[9];
#pragma unroll
  for (int m = 0; m < 9; m++) {
    int jj = (q + 4 - m) & 15;
    vv0[m] = C32(vsh[jj * 2]);
    vv1[m] = C32(vsh[jj * 2 + 1]);
  }

  c32 lp = csel(vv0[0], vv1[0], lb0);
  lp = cmul(lp, csel(vv0[1], vv1[1], lb1));
  lp = cmul(lp, csel(vv0[2], vv1[2], lb2));
  lp = cmul(lp, csel(vv0[6], vv1[6], lb3));
  lp = cmul(lp, csel(vv0[7], vv1[7], lb4));
  lp = cmul(lp, csel(vv0[8], vv1[8], lb5));

  c32 a[8];
#pragma unroll
  for (int r = 0; r < 8; r++) {
    c32 tt = cmul(((r & 1) ? vv1[3] : vv0[3]), (((r >> 1) & 1) ? vv1[4] : vv0[4]));
    tt = cmul(tt, (((r >> 2) & 1) ? vv1[5] : vv0[5]));
    a[r] = cmul(lp, tt);
  }

  // pre-halved ring weight for layer l, window pair (m, m-1)
#define PHW(l, m) phish[(l) * 16 + ((q + 4 - (m)) & 15)]

  c32 u[4];
  // ---- D0 (terms m=1..8) ----
  {
    float L = fsgn(lb1 ^ lb0, PHW(0, 1)) + fsgn(lb2 ^ lb1, PHW(0, 2))
            + fsgn(lb4 ^ lb3, PHW(0, 7)) + fsgn(lb5 ^ lb4, PHW(0, 8));
    diag8(a, L, fsgn(lb2, PHW(0, 3)), PHW(0, 4), PHW(0, 5), fsgn(lb3, PHW(0, 6)));
  }
  // ---- S1 on window bits 1..7 (layer slot 0) ----
  loadU(ugsh, 0 * 16 + ((q + 3) & 15), u); xgate(a, u, 1, lane);   // m=1
  loadU(ugsh, 0 * 16 + ((q + 2) & 15), u); xgate(a, u, 2, lane);   // m=2
  loadU(ugsh, 0 * 16 + ((q + 1) & 15), u); rgate<1>(a, u);         // m=3
  loadU(ugsh, 0 * 16 + ( q          ), u); rgate<2>(a, u);         // m=4
  loadU(ugsh, 0 * 16 + ((q - 1) & 15), u); rgate<4>(a, u);         // m=5
  loadU(ugsh, 0 * 16 + ((q - 2) & 15), u); xgate(a, u, 3, lane);   // m=6
  loadU(ugsh, 0 * 16 + ((q - 3) & 15), u); xgate(a, u, 4, lane);   // m=7
  // ---- D1 (terms m=2..7) ----
  {
    float L = fsgn(lb2 ^ lb1, PHW(1, 2)) + fsgn(lb4 ^ lb3, PHW(1, 7));
    diag8(a, L, fsgn(lb2, PHW(1, 3)), PHW(1, 4), PHW(1, 5), fsgn(lb3, PHW(1, 6)));
  }
  // ---- S2 on window bits 2..6 (layer slot 1) ----
  loadU(ugsh, 1 * 16 + ((q + 2) & 15), u); xgate(a, u, 2, lane);   // m=2
  loadU(ugsh, 1 * 16 + ((q + 1) & 15), u); rgate<1>(a, u);         // m=3
  loadU(ugsh, 1 * 16 + ( q          ), u); rgate<2>(a, u);         // m=4
  loadU(ugsh, 1 * 16 + ((q - 1) & 15), u); rgate<4>(a, u);         // m=5
  loadU(ugsh, 1 * 16 + ((q - 2) & 15), u); xgate(a, u, 3, lane);   // m=6
  // ---- D2 (terms m=3..6) ----
  diag8(a, 0.f, fsgn(lb2, PHW(2, 3)), PHW(2, 4), PHW(2, 5), fsgn(lb3, PHW(2, 6)));
  // ---- S3 on window bits 3..5 (layer slot 2) ----
  loadU(ugsh, 2 * 16 + ((q + 1) & 15), u); rgate<1>(a, u);         // m=3
  loadU(ugsh, 2 * 16 + ( q          ), u); rgate<2>(a, u);         // m=4
  loadU(ugsh, 2 * 16 + ((q - 1) & 15), u); rgate<4>(a, u);         // m=5
  // ---- D3: pure phase before Z measurement -> unobservable, dropped ----

  // ---- measure Z_q: window bit 4 = reg bit 1 ----
  float z = 0.f;
#pragma unroll
  for (int r = 0; r < 8; r++) {
    float p = a[r].x * a[r].x + a[r].y * a[r].y;
    z += ((r >> 1) & 1) ? -p : p;
  }
#pragma unroll
  for (int off = 32; off > 0; off >>= 1) z += __shfl_xor(z, off, 64);
  if (lane == 0) zsh[q] = z;
  __syncthreads();

  // ---- in-block MLP decode ----
  if (tid < 32) {
    float hj = b1[tid];
#pragma unroll
    for (int qq = 0; qq < 16; qq++) hj += zsh[qq] * W1[qq * 32 + tid];
    hsh[tid] = fmaxf(hj, 0.f);
  }
  __syncthreads();
  if (tid < 10) {
    float o = b2[tid];
#pragma unroll
    for (int j = 0; j < 32; j++) o += hsh[j] * W2[j * 10 + tid];
    out[b * 10 + tid] = o;
  }
#undef PHW
}

// --------------------------- launcher --------------------------------------

extern "C" void kernel_launch(void* const* d_in, const int* in_sizes, int n_in,
                              void* d_out, int out_size, void* d_ws, size_t ws_size,
                              hipStream_t stream) {
  const float* x     = (const float*)d_in[0];
  const float* Wenc  = (const float*)d_in[1];
  const float* benc  = (const float*)d_in[2];
  const float* theta = (const float*)d_in[3];
  const float* phi   = (const float*)d_in[4];
  const float* W1    = (const float*)d_in[5];
  const float* b1    = (const float*)d_in[6];
  const float* W2    = (const float*)d_in[7];
  const float* b2    = (const float*)d_in[8];
  float* out = (float*)d_out;

  k_all<<<256, 1024, 0, stream>>>(x, Wenc, benc, theta, phi, W1, b1, W2, b2, out);
}